// Round 11
// baseline (237.380 us; speedup 1.0000x reference)
//
#include <hip/hip_runtime.h>

#define CLAMP_MIN_F (-10.0f)
#define CLAMP_MAX_F (10.0f)
#define BATCH 8
#define CHUNK 2048       // dst nodes per chunk (LDS acc + E slice)
#define CHUNK_LOG 11
#define TILE 1024        // src nodes per tile (L1-resident working set)
#define TILE_LOG 10
#define GSPLIT 5         // tile-groups (blocks) per chunk
#define EPB 16384        // edges per binning block
#define TB_BIN 1024      // threads for hist/scatter
#define MAXCELL 8192     // scan capacity

// ---- prep: transpose o_pre (B,N) -> (N,B); zero cell totals ----------------
__global__ void prep_o_kernel(const float* __restrict__ o_pre,
                              float* __restrict__ o_preT,
                              unsigned* __restrict__ total,
                              int N) {
    int n = blockIdx.x * blockDim.x + threadIdx.x;
    if (n < MAXCELL) total[n] = 0u;
    if (n >= N) return;
    float o[BATCH];
    #pragma unroll
    for (int b = 0; b < BATCH; ++b) o[b] = o_pre[b * N + n];
    float4* op = (float4*)&o_preT[(size_t)n * BATCH];
    op[0] = make_float4(o[0], o[1], o[2], o[3]);
    op[1] = make_float4(o[4], o[5], o[6], o[7]);
}

// ---- pass 1: per-block cell histogram + direct space reservation -----------
__global__ void hist_reserve_kernel(const int* __restrict__ src,
                                    const int* __restrict__ dst,
                                    unsigned* __restrict__ total,
                                    unsigned* __restrict__ offs0,
                                    int edges, int NT, int KPAD) {
    extern __shared__ unsigned sh[];
    int bid = blockIdx.x;
    for (int k = threadIdx.x; k < KPAD; k += blockDim.x) sh[k] = 0u;
    __syncthreads();
    int start = bid * EPB;
    int end = min(edges, start + EPB);
    for (int i = start + threadIdx.x; i < end; i += blockDim.x) {
        int cell = (dst[i] >> CHUNK_LOG) * NT + (src[i] >> TILE_LOG);
        atomicAdd(&sh[cell], 1u);
    }
    __syncthreads();
    for (int k = threadIdx.x; k < KPAD; k += blockDim.x) {
        unsigned c = sh[k];
        offs0[(size_t)bid * KPAD + k] = c ? atomicAdd(&total[k], c) : 0u;
    }
}

// ---- pass 2: exclusive scan over cell totals (<=8192), 1024 thr x 8 --------
__global__ void scan8_kernel(const unsigned* __restrict__ total,
                             unsigned* __restrict__ base,
                             int KPAD) {
    __shared__ unsigned s1[1024];
    __shared__ unsigned s2[1024];
    int t = threadIdx.x;
    unsigned v[8];
    unsigned sum = 0;
    #pragma unroll
    for (int j = 0; j < 8; ++j) {
        int idx = 8 * t + j;
        v[j] = (idx < KPAD) ? total[idx] : 0u;
        sum += v[j];
    }
    s1[t] = sum;
    __syncthreads();
    unsigned* cur = s1;
    unsigned* nxt = s2;
    for (int off = 1; off < 1024; off <<= 1) {
        unsigned x = cur[t];
        if (t >= off) x += cur[t - off];
        nxt[t] = x;
        __syncthreads();
        unsigned* tmp = cur; cur = nxt; nxt = tmp;
    }
    unsigned incl = cur[t];
    unsigned run = incl - sum;   // exclusive
    #pragma unroll
    for (int j = 0; j < 8; ++j) {
        base[8 * t + j] = run;
        run += v[j];
    }
    if (t == 1023) base[MAXCELL] = incl;
}

// ---- pass 3: scatter edges into 8B cell-sorted records ---------------------
// key = (dst_local:11 bits << 17) | src (src < 2^17)
__global__ void scatter_kernel(const int* __restrict__ src,
                               const int* __restrict__ dst,
                               const float* __restrict__ w,
                               const unsigned* __restrict__ offs0,
                               const unsigned* __restrict__ base,
                               int2* __restrict__ recS,
                               int edges, int NT, int KPAD) {
    extern __shared__ unsigned loffs[];
    int bid = blockIdx.x;
    for (int k = threadIdx.x; k < KPAD; k += blockDim.x)
        loffs[k] = base[k] + offs0[(size_t)bid * KPAD + k];
    __syncthreads();
    int start = bid * EPB;
    int end = min(edges, start + EPB);
    for (int i = start + threadIdx.x; i < end; i += blockDim.x) {
        int d = dst[i];
        int s = src[i];
        float wv = w[i];
        int cell = (d >> CHUNK_LOG) * NT + (s >> TILE_LOG);
        unsigned pos = atomicAdd(&loffs[cell], 1u);
        unsigned key = (((unsigned)d & (CHUNK - 1)) << 17) | (unsigned)s;
        recS[pos] = make_int2((int)key, __float_as_int(wv));
    }
}

// ---- pass 4: per-(chunk, tile-group) accumulate ------------------------------
// Block owns chunk c (acc + E slice in LDS, 128 KB) and a range of src tiles.
// Cells processed one at a time with a barrier: the cell's o_preT working set
// (<=1024 nodes = 32 KB) stays L1-resident, so repeated src hits are L1 hits.
// Partial acc written to scratch slice g (plain coalesced stores, no atomics).
__global__ __launch_bounds__(1024)
void accum_kernel(const int2* __restrict__ recS,
                  const unsigned* __restrict__ cellBase,
                  const float* __restrict__ o_preT,   // (N,B)
                  const float* __restrict__ E,        // (B,N)
                  float* __restrict__ scratch,        // (GSPLIT, N, B)
                  int N, int NT, int BN) {
    __shared__ float acc[CHUNK * BATCH];     // 64 KB
    __shared__ float e_lds[CHUNK * BATCH];   // 64 KB
    int c = blockIdx.x / GSPLIT;   // chunk
    int g = blockIdx.x % GSPLIT;   // tile-group
    int ns = c << CHUNK_LOG;
    int cnt = min(CHUNK, N - ns);
    int bs = blockDim.x;

    for (int i = threadIdx.x; i < CHUNK * BATCH; i += bs) acc[i] = 0.f;
    // stage E slice: coalesced per batch row
    for (int i = threadIdx.x; i < BATCH * cnt; i += bs) {
        int b = i / cnt;
        int n = i - b * cnt;
        e_lds[n * BATCH + b] = E[(size_t)b * N + ns + n];
    }
    __syncthreads();

    int tpg = (NT + GSPLIT - 1) / GSPLIT;
    int t0 = g * tpg;
    int t1 = min(NT, t0 + tpg);
    int b = threadIdx.x & 7;           // batch lane
    int grp = threadIdx.x >> 3;        // group id (0..127)
    int ngrp = bs >> 3;

    for (int t = t0; t < t1; ++t) {
        int cell = c * NT + t;
        unsigned r0 = cellBase[cell], r1 = cellBase[cell + 1];
        for (unsigned r = r0 + grp; r < r1; r += ngrp) {
            int2 rec = recS[r];                      // broadcast within group
            unsigned key = (unsigned)rec.x;
            float Oj = o_preT[((size_t)(key & 0x1FFFFu) << 3) + b];  // merged 32B
            int dl = (int)(key >> 17);
            float En = e_lds[dl * BATCH + b];
            float df = Oj - En;
            float sg = (df > 0.f) ? 1.f : ((df < 0.f) ? -1.f : 0.f);
            atomicAdd(&acc[dl * BATCH + b], Oj * __int_as_float(rec.y) * sg);
        }
        __syncthreads();   // keep waves cell-aligned -> L1 working set = 1 cell
    }

    // write partial slice (coalesced, no atomics)
    float* out = &scratch[(size_t)g * BN + ((size_t)ns * BATCH)];
    for (int i = threadIdx.x; i < cnt * BATCH; i += bs) out[i] = acc[i];
}

// ---- finalize: sum GSPLIT slices + chem_influence, epilogue -----------------
__global__ void finalize_g(const float* __restrict__ E,        // (B,N)
                           const float* __restrict__ chem_in,  // (B,N)
                           const float* __restrict__ scratch,  // (GSPLIT,N,B)
                           const float* __restrict__ thr,
                           const float* __restrict__ decay,
                           float* __restrict__ new_o,          // (B,N)
                           float* __restrict__ new_e,          // (B,N)
                           int N, int BN) {
    int n = blockIdx.x * blockDim.x + threadIdx.x;
    if (n >= N) return;
    float c[BATCH];
    #pragma unroll
    for (int b = 0; b < BATCH; ++b) c[b] = 0.f;
    for (int g = 0; g < GSPLIT; ++g) {
        const float4* cp = (const float4*)&scratch[(size_t)g * BN + (size_t)n * BATCH];
        float4 c0 = cp[0], c1 = cp[1];
        c[0]+=c0.x; c[1]+=c0.y; c[2]+=c0.z; c[3]+=c0.w;
        c[4]+=c1.x; c[5]+=c1.y; c[6]+=c1.z; c[7]+=c1.w;
    }
    float t = thr[n];
    float dc = decay[n];
    #pragma unroll
    for (int b = 0; b < BATCH; ++b) {
        int i = b * N + n;
        float e = E[i];
        float S = e + chem_in[i] + c[b];
        S = fminf(fmaxf(S, CLAMP_MIN_F), CLAMP_MAX_F);
        bool gt = S > t;
        float no = fmaxf(S - t, 0.f);
        float ne = gt ? no : ((S == e) ? (e - dc) : S);
        new_o[i] = no;
        new_e[i] = ne;
    }
}

// ---------------- fallback: R3 atomic path ----------------------------------
__global__ void prep_kernel(const float* __restrict__ chem_in,
                            const float* __restrict__ o_pre,
                            const float* __restrict__ E,
                            float* __restrict__ chemT,
                            float* __restrict__ o_preT,
                            float* __restrict__ E_T,
                            int N) {
    int n = blockIdx.x * blockDim.x + threadIdx.x;
    if (n >= N) return;
    float c[BATCH], o[BATCH], ee[BATCH];
    #pragma unroll
    for (int b = 0; b < BATCH; ++b) {
        c[b]  = chem_in[b * N + n];
        o[b]  = o_pre[b * N + n];
        ee[b] = E[b * N + n];
    }
    float4* cp = (float4*)&chemT[(size_t)n * BATCH];
    cp[0] = make_float4(c[0], c[1], c[2], c[3]);
    cp[1] = make_float4(c[4], c[5], c[6], c[7]);
    float4* op = (float4*)&o_preT[(size_t)n * BATCH];
    op[0] = make_float4(o[0], o[1], o[2], o[3]);
    op[1] = make_float4(o[4], o[5], o[6], o[7]);
    float4* ep = (float4*)&E_T[(size_t)n * BATCH];
    ep[0] = make_float4(ee[0], ee[1], ee[2], ee[3]);
    ep[1] = make_float4(ee[4], ee[5], ee[6], ee[7]);
}
__global__ void edge_scatter_eb(const int* __restrict__ src,
                                const int* __restrict__ dst,
                                const float* __restrict__ w,
                                const float* __restrict__ o_preT,
                                const float* __restrict__ E_T,
                                float* __restrict__ chemT,
                                int edges) {
    int t = blockIdx.x * blockDim.x + threadIdx.x;
    int e = t >> 3;
    int b = t & 7;
    if (e >= edges) return;
    int s = src[e]; int d = dst[e]; float we = w[e];
    float Oj = o_preT[(size_t)s * BATCH + b];
    float En = E_T[(size_t)d * BATCH + b];
    float diff = Oj - En;
    float sg = (diff > 0.0f) ? 1.0f : ((diff < 0.0f) ? -1.0f : 0.0f);
    atomicAdd(&chemT[(size_t)d * BATCH + b], Oj * we * sg);
}
__global__ void finalize_nb(const float* __restrict__ E,
                            const float* __restrict__ chemT,
                            const float* __restrict__ thr,
                            const float* __restrict__ decay,
                            float* __restrict__ new_o,
                            float* __restrict__ new_e, int N) {
    int n = blockIdx.x * blockDim.x + threadIdx.x;
    if (n >= N) return;
    const float4* cp = (const float4*)&chemT[(size_t)n * BATCH];
    float4 c0 = cp[0], c1 = cp[1];
    float c[BATCH] = {c0.x, c0.y, c0.z, c0.w, c1.x, c1.y, c1.z, c1.w};
    float t = thr[n];
    float dc = decay[n];
    #pragma unroll
    for (int b = 0; b < BATCH; ++b) {
        int i = b * N + n;
        float e = E[i];
        float S = fminf(fmaxf(e + c[b], CLAMP_MIN_F), CLAMP_MAX_F);
        bool gt = S > t;
        float no = fmaxf(S - t, 0.0f);
        float ne = gt ? no : ((S == e) ? (e - dc) : S);
        new_o[i] = no;
        new_e[i] = ne;
    }
}

static inline size_t align256(size_t x) { return (x + 255) & ~(size_t)255; }

extern "C" void kernel_launch(void* const* d_in, const int* in_sizes, int n_in,
                              void* d_out, int out_size, void* d_ws, size_t ws_size,
                              hipStream_t stream) {
    const float* chem_influence = (const float*)d_in[0];
    const float* E              = (const float*)d_in[1];
    const int*   src            = (const int*)d_in[3];
    const int*   dst            = (const int*)d_in[4];
    const float* w              = (const float*)d_in[5];
    const float* o_pre          = (const float*)d_in[6];
    const float* threshold      = (const float*)d_in[7];
    const float* decay          = (const float*)d_in[8];

    const int edges = in_sizes[3];
    const int BN    = in_sizes[0];   // B * N
    const int N     = in_sizes[7];   // threshold is (N,)

    float* new_o = (float*)d_out;
    float* new_e = (float*)d_out + BN;

    const int TB = 256;
    int nblk = (N + TB - 1) / TB;

    const int NT    = (N + TILE - 1) >> TILE_LOG;    // src tiles
    const int NC    = (N + CHUNK - 1) >> CHUNK_LOG;  // dst chunks
    const int CELLS = NC * NT;
    const int KPAD  = (CELLS + 63) & ~63;
    const int NB    = (edges + EPB - 1) / EPB;       // binning blocks

    // ws layout
    size_t off = 0;
    size_t opreT_off  = off; off += align256((size_t)BN * 4);
    size_t base_off   = off; off += align256((size_t)(MAXCELL + 1) * 4);
    size_t total_off  = off; off += align256((size_t)MAXCELL * 4);
    size_t offs0_off  = off; off += align256((size_t)NB * KPAD * 4);
    size_t rec_off    = off; off += align256((size_t)edges * 8);
    size_t scr_off    = off; off += align256((size_t)GSPLIT * BN * 4);
    size_t need = off;

    char* wsb = (char*)d_ws;

    if (CELLS <= MAXCELL && N <= (1 << 17) && ws_size >= need) {
        float*    o_preT  = (float*)(wsb + opreT_off);
        unsigned* base    = (unsigned*)(wsb + base_off);
        unsigned* total   = (unsigned*)(wsb + total_off);
        unsigned* offs0   = (unsigned*)(wsb + offs0_off);
        int2*     recS    = (int2*)(wsb + rec_off);
        float*    scratch = (float*)(wsb + scr_off);

        size_t shBytes = (size_t)KPAD * 4;

        prep_o_kernel<<<nblk, TB, 0, stream>>>(o_pre, o_preT, total, N);
        hist_reserve_kernel<<<NB, TB_BIN, shBytes, stream>>>(src, dst, total, offs0,
                                                             edges, NT, KPAD);
        scan8_kernel<<<1, 1024, 0, stream>>>(total, base, KPAD);
        scatter_kernel<<<NB, TB_BIN, shBytes, stream>>>(src, dst, w, offs0, base,
                                                        recS, edges, NT, KPAD);
        accum_kernel<<<NC * GSPLIT, 1024, 0, stream>>>(recS, base, o_preT, E,
                                                       scratch, N, NT, BN);
        finalize_g<<<nblk, TB, 0, stream>>>(E, chem_influence, scratch,
                                            threshold, decay, new_o, new_e, N, BN);
    } else if (ws_size >= 3 * (size_t)BN * 4) {
        float* chemT  = (float*)d_ws;
        float* o_preT = chemT + BN;
        float* E_T    = o_preT + BN;
        prep_kernel<<<nblk, TB, 0, stream>>>(chem_influence, o_pre, E,
                                             chemT, o_preT, E_T, N);
        long long ethreads = (long long)edges * BATCH;
        int gblk = (int)((ethreads + TB - 1) / TB);
        edge_scatter_eb<<<gblk, TB, 0, stream>>>(src, dst, w, o_preT, E_T,
                                                 chemT, edges);
        finalize_nb<<<nblk, TB, 0, stream>>>(E, chemT, threshold, decay,
                                             new_o, new_e, N);
    }
}

// Round 12
// 92.426 us; speedup vs baseline: 2.5683x; 2.5683x over previous
//
#include <hip/hip_runtime.h>

#define CLAMP_MIN_F (-10.0f)
#define CLAMP_MAX_F (10.0f)
#define BATCH 8
#define R_LOG 5          // 32 nodes per bucket
#define RNODES 32
#define ASTR 9           // LDS row stride (pad 8 -> 9)
#define EPB 16384        // edges per binning block
#define TB_BIN 1024      // threads for hist/scatter
#define MAX4K 4096       // scan capacity (K must be <= 4095)
#define SCHUNK 2048      // records per in-bucket sort chunk (16KB LDS)
#define MAXH (SCHUNK / 256)   // held records per thread per chunk

// ---- prep: transpose o_pre (B,N) -> (N,B); zero bucket totals --------------
__global__ void prep_o_kernel(const float* __restrict__ o_pre,
                              float* __restrict__ o_preT,
                              unsigned* __restrict__ total,
                              int N) {
    int n = blockIdx.x * blockDim.x + threadIdx.x;
    if (n < MAX4K) total[n] = 0u;
    if (n >= N) return;
    float o[BATCH];
    #pragma unroll
    for (int b = 0; b < BATCH; ++b) o[b] = o_pre[b * N + n];
    float4* op = (float4*)&o_preT[(size_t)n * BATCH];
    op[0] = make_float4(o[0], o[1], o[2], o[3]);
    op[1] = make_float4(o[4], o[5], o[6], o[7]);
}

// ---- pass 1: per-block histogram + direct space reservation ----------------
__global__ void hist_reserve_kernel(const int* __restrict__ dst,
                                    unsigned* __restrict__ total,
                                    unsigned* __restrict__ offs0,
                                    int edges, int KPAD) {
    __shared__ unsigned sh[MAX4K];
    int bid = blockIdx.x;
    for (int k = threadIdx.x; k < KPAD; k += blockDim.x) sh[k] = 0u;
    __syncthreads();
    int start = bid * EPB;
    int end = min(edges, start + EPB);
    for (int i = start + threadIdx.x; i < end; i += blockDim.x)
        atomicAdd(&sh[((unsigned)dst[i]) >> R_LOG], 1u);
    __syncthreads();
    for (int k = threadIdx.x; k < KPAD; k += blockDim.x) {
        unsigned c = sh[k];
        offs0[(size_t)bid * KPAD + k] = c ? atomicAdd(&total[k], c) : 0u;
    }
}

// ---- pass 2: exclusive scan over bucket totals (<=4096), 1024 thr x 4 ------
__global__ void scan4_kernel(const unsigned* __restrict__ total,
                             unsigned* __restrict__ base,
                             int KPAD) {
    __shared__ unsigned s1[1024];
    __shared__ unsigned s2[1024];
    int t = threadIdx.x;
    unsigned v0 = (4 * t     < KPAD) ? total[4 * t]     : 0u;
    unsigned v1 = (4 * t + 1 < KPAD) ? total[4 * t + 1] : 0u;
    unsigned v2 = (4 * t + 2 < KPAD) ? total[4 * t + 2] : 0u;
    unsigned v3 = (4 * t + 3 < KPAD) ? total[4 * t + 3] : 0u;
    unsigned sum = v0 + v1 + v2 + v3;
    s1[t] = sum;
    __syncthreads();
    unsigned* cur = s1;
    unsigned* nxt = s2;
    for (int off = 1; off < 1024; off <<= 1) {
        unsigned x = cur[t];
        if (t >= off) x += cur[t - off];
        nxt[t] = x;
        __syncthreads();
        unsigned* tmp = cur; cur = nxt; nxt = tmp;
    }
    unsigned incl = cur[t];
    unsigned excl = incl - sum;
    base[4 * t]     = excl;
    base[4 * t + 1] = excl + v0;
    base[4 * t + 2] = excl + v0 + v1;
    base[4 * t + 3] = excl + v0 + v1 + v2;
    if (t == 1023) base[4096] = incl;
}

// ---- pass 3: scatter edges into 8B bucket-sorted records -------------------
// key = (dst_local:5 bits << 26) | src   (src < 2^26)
__global__ void scatter_kernel(const int* __restrict__ src,
                               const int* __restrict__ dst,
                               const float* __restrict__ w,
                               const unsigned* __restrict__ offs0,
                               const unsigned* __restrict__ base,
                               int2* __restrict__ recS,
                               int edges, int KPAD) {
    __shared__ unsigned loffs[MAX4K];
    int bid = blockIdx.x;
    for (int k = threadIdx.x; k < KPAD; k += blockDim.x)
        loffs[k] = base[k] + offs0[(size_t)bid * KPAD + k];
    __syncthreads();
    int start = bid * EPB;
    int end = min(edges, start + EPB);
    for (int i = start + threadIdx.x; i < end; i += blockDim.x) {
        int d = dst[i];
        int s = src[i];
        float wv = w[i];
        unsigned k = ((unsigned)d) >> R_LOG;
        unsigned pos = atomicAdd(&loffs[k], 1u);
        unsigned key = (((unsigned)d & (RNODES - 1)) << 26) | (unsigned)s;
        recS[pos] = make_int2((int)key, __float_as_int(wv));
    }
}

// ---- pass 4: per-bucket counting-sort + register accumulate + finalize -----
// Phase A: thread-per-record takes a slot via LDS counter atomicAdd (3.2M
// lane-atomics total, 8x fewer than before) and scatters records dl-sorted
// into LDS. Phase B: 8-lane group g owns node dl=g; scans ITS records from
// LDS, accumulating in a REGISTER (zero accumulation atomics; En hoisted).
__global__ __launch_bounds__(256)
void accum_kernel(const int2* __restrict__ recS,
                  const unsigned* __restrict__ base,
                  const float* __restrict__ o_preT,   // (N,B)
                  const float* __restrict__ E,        // (B,N)
                  const float* __restrict__ chem_in,  // (B,N)
                  const float* __restrict__ thr,
                  const float* __restrict__ decay,
                  float* __restrict__ new_o,          // (B,N)
                  float* __restrict__ new_e,          // (B,N)
                  int N) {
    __shared__ int2 srec[SCHUNK];                 // 16 KB sorted records
    __shared__ float e_lds[RNODES * ASTR];
    __shared__ float acc_st[RNODES * ASTR];
    __shared__ unsigned cnt[RNODES];
    __shared__ unsigned sstart[RNODES + 1];
    int k = blockIdx.x;
    int ns = k << R_LOG;
    int cnt_n = min(RNODES, N - ns);
    int tid = threadIdx.x;

    for (int i = tid; i < RNODES * BATCH; i += blockDim.x) {
        int b = i >> R_LOG;
        int n = i & (RNODES - 1);
        if (n < cnt_n) e_lds[n * ASTR + b] = E[(size_t)b * N + ns + n];
    }
    __syncthreads();

    int b = tid & 7;            // batch lane
    int g = tid >> 3;           // owned node (0..31)
    float En = e_lds[g * ASTR + b];
    float accv = 0.f;

    unsigned b0 = base[k], b1 = base[k + 1];
    for (unsigned cs = b0; cs < b1; cs += SCHUNK) {
        unsigned m = min((unsigned)SCHUNK, b1 - cs);
        if (tid < RNODES) cnt[tid] = 0u;
        __syncthreads();

        // Phase A: claim slots
        int2 hrec[MAXH];
        unsigned hmeta[MAXH];
        #pragma unroll
        for (int j = 0; j < MAXH; ++j) {
            unsigned i = (unsigned)tid + (unsigned)j * blockDim.x;
            if (i < m) {
                int2 rec = recS[cs + i];
                unsigned dl = ((unsigned)rec.x >> 26) & (RNODES - 1);
                unsigned pos = atomicAdd(&cnt[dl], 1u);
                hrec[j] = rec;
                hmeta[j] = (dl << 16) | pos;
            } else {
                hmeta[j] = 0xFFFFFFFFu;
            }
        }
        __syncthreads();
        if (tid == 0) {
            unsigned run = 0;
            for (int d = 0; d < RNODES; ++d) { sstart[d] = run; run += cnt[d]; }
            sstart[RNODES] = run;
        }
        __syncthreads();
        // Phase A2: scatter into sorted LDS array
        #pragma unroll
        for (int j = 0; j < MAXH; ++j) {
            if (hmeta[j] != 0xFFFFFFFFu) {
                unsigned dl = hmeta[j] >> 16;
                unsigned pos = hmeta[j] & 0xFFFFu;
                srec[sstart[dl] + pos] = hrec[j];
            }
        }
        __syncthreads();

        // Phase B: group g scans its own records; register accumulate
        unsigned st = sstart[g];
        unsigned en = st + cnt[g];
        for (unsigned r = st; r < en; ++r) {
            int2 rec = srec[r];                        // broadcast in group
            unsigned s = (unsigned)rec.x & 0x3FFFFFFu;
            float Oj = o_preT[((size_t)s << 3) + b];   // merged 32B / group
            float wv = __int_as_float(rec.y);
            float df = Oj - En;
            float sg = (df > 0.f) ? 1.f : ((df < 0.f) ? -1.f : 0.f);
            accv += Oj * wv * sg;
        }
        __syncthreads();   // before cnt/srec reuse
    }

    acc_st[g * ASTR + b] = accv;
    __syncthreads();

    // fused finalize (coalesced global IO)
    for (int i = tid; i < RNODES * BATCH; i += blockDim.x) {
        int bb = i >> R_LOG;
        int n = i & (RNODES - 1);
        if (n >= cnt_n) continue;
        float e = e_lds[n * ASTR + bb];
        float S = e + chem_in[(size_t)bb * N + ns + n] + acc_st[n * ASTR + bb];
        S = fminf(fmaxf(S, CLAMP_MIN_F), CLAMP_MAX_F);
        float t  = thr[ns + n];
        float dc = decay[ns + n];
        bool gt = S > t;
        float no = fmaxf(S - t, 0.f);
        float ne = gt ? no : ((S == e) ? (e - dc) : S);
        new_o[(size_t)bb * N + ns + n] = no;
        new_e[(size_t)bb * N + ns + n] = ne;
    }
}

// ---------------- fallback: R3 atomic path ----------------------------------
__global__ void prep_kernel(const float* __restrict__ chem_in,
                            const float* __restrict__ o_pre,
                            const float* __restrict__ E,
                            float* __restrict__ chemT,
                            float* __restrict__ o_preT,
                            float* __restrict__ E_T,
                            int N) {
    int n = blockIdx.x * blockDim.x + threadIdx.x;
    if (n >= N) return;
    float c[BATCH], o[BATCH], ee[BATCH];
    #pragma unroll
    for (int b = 0; b < BATCH; ++b) {
        c[b]  = chem_in[b * N + n];
        o[b]  = o_pre[b * N + n];
        ee[b] = E[b * N + n];
    }
    float4* cp = (float4*)&chemT[(size_t)n * BATCH];
    cp[0] = make_float4(c[0], c[1], c[2], c[3]);
    cp[1] = make_float4(c[4], c[5], c[6], c[7]);
    float4* op = (float4*)&o_preT[(size_t)n * BATCH];
    op[0] = make_float4(o[0], o[1], o[2], o[3]);
    op[1] = make_float4(o[4], o[5], o[6], o[7]);
    float4* ep = (float4*)&E_T[(size_t)n * BATCH];
    ep[0] = make_float4(ee[0], ee[1], ee[2], ee[3]);
    ep[1] = make_float4(ee[4], ee[5], ee[6], ee[7]);
}
__global__ void edge_scatter_eb(const int* __restrict__ src,
                                const int* __restrict__ dst,
                                const float* __restrict__ w,
                                const float* __restrict__ o_preT,
                                const float* __restrict__ E_T,
                                float* __restrict__ chemT,
                                int edges) {
    int t = blockIdx.x * blockDim.x + threadIdx.x;
    int e = t >> 3;
    int b = t & 7;
    if (e >= edges) return;
    int s = src[e]; int d = dst[e]; float we = w[e];
    float Oj = o_preT[(size_t)s * BATCH + b];
    float En = E_T[(size_t)d * BATCH + b];
    float diff = Oj - En;
    float sg = (diff > 0.0f) ? 1.0f : ((diff < 0.0f) ? -1.0f : 0.0f);
    atomicAdd(&chemT[(size_t)d * BATCH + b], Oj * we * sg);
}
__global__ void finalize_nb(const float* __restrict__ E,
                            const float* __restrict__ chemT,
                            const float* __restrict__ thr,
                            const float* __restrict__ decay,
                            float* __restrict__ new_o,
                            float* __restrict__ new_e, int N) {
    int n = blockIdx.x * blockDim.x + threadIdx.x;
    if (n >= N) return;
    const float4* cp = (const float4*)&chemT[(size_t)n * BATCH];
    float4 c0 = cp[0], c1 = cp[1];
    float c[BATCH] = {c0.x, c0.y, c0.z, c0.w, c1.x, c1.y, c1.z, c1.w};
    float t = thr[n];
    float dc = decay[n];
    #pragma unroll
    for (int b = 0; b < BATCH; ++b) {
        int i = b * N + n;
        float e = E[i];
        float S = fminf(fmaxf(e + c[b], CLAMP_MIN_F), CLAMP_MAX_F);
        bool gt = S > t;
        float no = fmaxf(S - t, 0.0f);
        float ne = gt ? no : ((S == e) ? (e - dc) : S);
        new_o[i] = no;
        new_e[i] = ne;
    }
}

static inline size_t align256(size_t x) { return (x + 255) & ~(size_t)255; }

extern "C" void kernel_launch(void* const* d_in, const int* in_sizes, int n_in,
                              void* d_out, int out_size, void* d_ws, size_t ws_size,
                              hipStream_t stream) {
    const float* chem_influence = (const float*)d_in[0];
    const float* E              = (const float*)d_in[1];
    const int*   src            = (const int*)d_in[3];
    const int*   dst            = (const int*)d_in[4];
    const float* w              = (const float*)d_in[5];
    const float* o_pre          = (const float*)d_in[6];
    const float* threshold      = (const float*)d_in[7];
    const float* decay          = (const float*)d_in[8];

    const int edges = in_sizes[3];
    const int BN    = in_sizes[0];   // B * N
    const int N     = in_sizes[7];   // threshold is (N,)

    float* new_o = (float*)d_out;
    float* new_e = (float*)d_out + BN;

    const int TB = 256;
    int nblk = (N + TB - 1) / TB;

    const int K    = (N + RNODES - 1) >> R_LOG;        // buckets (32 nodes)
    const int KPAD = (K + 63) & ~63;
    const int NB   = (edges + EPB - 1) / EPB;          // binning blocks

    // ws layout
    size_t off = 0;
    size_t opreT_off  = off; off += align256((size_t)BN * 4);
    size_t base_off   = off; off += align256((size_t)(MAX4K + 1) * 4);
    size_t total_off  = off; off += align256((size_t)MAX4K * 4);
    size_t offs0_off  = off; off += align256((size_t)NB * KPAD * 4);
    size_t rec_off    = off; off += align256((size_t)edges * 8);
    size_t need = off;

    char* wsb = (char*)d_ws;

    if (K <= MAX4K - 1 && ws_size >= need) {
        float*    o_preT = (float*)(wsb + opreT_off);
        unsigned* base   = (unsigned*)(wsb + base_off);
        unsigned* total  = (unsigned*)(wsb + total_off);
        unsigned* offs0  = (unsigned*)(wsb + offs0_off);
        int2*     recS   = (int2*)(wsb + rec_off);

        prep_o_kernel<<<nblk, TB, 0, stream>>>(o_pre, o_preT, total, N);
        hist_reserve_kernel<<<NB, TB_BIN, 0, stream>>>(dst, total, offs0, edges, KPAD);
        scan4_kernel<<<1, 1024, 0, stream>>>(total, base, KPAD);
        scatter_kernel<<<NB, TB_BIN, 0, stream>>>(src, dst, w, offs0, base, recS, edges, KPAD);
        accum_kernel<<<K, TB, 0, stream>>>(recS, base, o_preT, E,
                                           chem_influence, threshold, decay,
                                           new_o, new_e, N);
    } else if (ws_size >= 3 * (size_t)BN * 4) {
        float* chemT  = (float*)d_ws;
        float* o_preT = chemT + BN;
        float* E_T    = o_preT + BN;
        prep_kernel<<<nblk, TB, 0, stream>>>(chem_influence, o_pre, E,
                                             chemT, o_preT, E_T, N);
        long long ethreads = (long long)edges * BATCH;
        int gblk = (int)((ethreads + TB - 1) / TB);
        edge_scatter_eb<<<gblk, TB, 0, stream>>>(src, dst, w, o_preT, E_T,
                                                 chemT, edges);
        finalize_nb<<<nblk, TB, 0, stream>>>(E, chemT, threshold, decay,
                                             new_o, new_e, N);
    }
}